// Round 14
// baseline (122.737 us; speedup 1.0000x reference)
//
#include <hip/hip_runtime.h>

#define W 256
#define H 256
#define HW (W*H)
#define NB 12
#define ROWS 16
#define BPI (H/ROWS)            // 16 strips per image
#define NBLK (NB*BPI)           // 192 blocks (1/CU, co-resident via cooperative launch)
#define NTHREADS 1024           // 16 waves; wave = row, lane = 4-px chunk
#define NUM_ITER 20
#define TVEPS 1e-8f
#define HPLANES 8
#define FLAG_MAGIC 0x5A170000

// d_ws layout: halo[NUM_ITER-1][NBLK][HPLANES][W] floats, then flags[NUM_ITER-1][3][NBLK].
// planes: 0:p1x(r0) 1:p1y(r0) 2:p2x(r0) 3:p2y(r0) 4:p1y(r1) 5:p2y(r1) 6:p1y(r15) 7:p2y(r15)
// flags : 0=A (wave0, planes0-3) 1=B (wave1, planes4-5) 2=C (wave15, planes6-7)
// R13 schedule + XCD-aware logical-block remap: CP dispatches blockIdx round-robin
// across 8 XCDs, so logical b=(blockIdx&7)*24+(blockIdx>>3) puts 24 CONSECUTIVE strips
// on each XCD -> 173/180 halo handshakes become same-XCD L2-local (vs 0 before).

__device__ __forceinline__ float aload(const float* p) {
    return __hip_atomic_load(p, __ATOMIC_RELAXED, __HIP_MEMORY_SCOPE_AGENT);
}
__device__ __forceinline__ void astore(float* p, float v) {
    __hip_atomic_store(p, v, __ATOMIC_RELAXED, __HIP_MEMORY_SCOPE_AGENT);
}
__device__ __forceinline__ void waitflag(const int* f, int tgt) {
    while (__hip_atomic_load(f, __ATOMIC_RELAXED, __HIP_MEMORY_SCOPE_AGENT) != tgt)
        __builtin_amdgcn_s_sleep(1);
    asm volatile("" ::: "memory");
}
__device__ __forceinline__ int peekflag(const int* f) {
    return __hip_atomic_load(f, __ATOMIC_RELAXED, __HIP_MEMORY_SCOPE_AGENT);
}
__device__ __forceinline__ void setflag(int* f, int tgt) {
    asm volatile("s_waitcnt vmcnt(0)" ::: "memory");   // data-before-flag; drain ~0 (deferred)
    __hip_atomic_store(f, tgt, __ATOMIC_RELAXED, __HIP_MEMORY_SCOPE_AGENT);
}
__device__ __forceinline__ float fastrcp(float x) { return __builtin_amdgcn_rcpf(x); }

#define LD4(dst, ptr) { const float4 _t = *reinterpret_cast<const float4*>(ptr); \
                        dst[0]=_t.x; dst[1]=_t.y; dst[2]=_t.z; dst[3]=_t.w; }
#define ST4(ptr, src) { float4 _t; _t.x=src[0]; _t.y=src[1]; _t.z=src[2]; _t.w=src[3]; \
                        *reinterpret_cast<float4*>(ptr) = _t; }

__global__ __launch_bounds__(NTHREADS, 1) void tvl1_xcd_kernel(
    const float* __restrict__ xin,
    const float* __restrict__ lam,
    const float* __restrict__ tau,
    const float* __restrict__ theta,
    const float* __restrict__ wxv,
    const float* __restrict__ wyv,
    float* __restrict__ uout,
    float* __restrict__ halo,
    int* __restrict__ flags)
{
    __shared__ float xu0[ROWS+1][W];   // u rows 0..16 (row16 maintained by wave 14)
    __shared__ float xu1[ROWS+1][W];
    __shared__ float xq1[ROWS][W];     // p1y rows 0..15
    __shared__ float xq2[ROWS][W];

    const int tid  = threadIdx.x;
    const int lane = tid & 63;
    const int wv   = tid >> 6;          // row within strip, 0..15
    const int x0   = lane << 2;
    // XCD-aware remap: physical blockIdx p lands on XCD p%8 (round-robin CP dispatch);
    // logical b groups 24 consecutive strips per XCD. Pure bijection on [0,192).
    const int b    = (blockIdx.x & 7) * (NBLK / 8) + (blockIdx.x >> 3);
    const int n    = b / BPI, bi = b % BPI;
    const int r0   = bi * ROWS;
    const int grow = r0 + wv;
    const bool notTop = (bi > 0), notBot = (bi < BPI-1);

    const float th0 = theta[0];
    const float tl  = th0 * lam[0];
    const float tt  = tau[0] / th0;
    const float wx0 = wxv[0], wx1 = wxv[1], wx2 = wxv[2];
    const float wy0 = wyv[0], wy1 = wyv[1], wy2 = wyv[2];

    const float* __restrict__ I0 = xin + (size_t)n * HW;
    const float* __restrict__ I1 = xin + (size_t)(NB + n) * HW;

    auto grad4 = [&](int row, float* rr, float* ggx, float* ggy) {
        #pragma unroll
        for (int c = 0; c < 4; ++c) {
            const int xc = x0 + c;
            const int idx = row * W + xc;
            const bool xm = xc > 0, xp = xc < W-1, ym = row > 0, yp = row < H-1;
            float a00=0.f,a01=0.f,a02=0.f,a10=0.f,a12=0.f,a20=0.f,a21=0.f,a22=0.f;
            if (ym) { a01=I1[idx-W]; if (xm) a00=I1[idx-W-1]; if (xp) a02=I1[idx-W+1]; }
            if (xm) a10=I1[idx-1];
            if (xp) a12=I1[idx+1];
            if (yp) { a21=I1[idx+W]; if (xm) a20=I1[idx+W-1]; if (xp) a22=I1[idx+W+1]; }
            ggx[c] = ((a02-a00) + 2.f*(a12-a10) + (a22-a20)) * (1.f/6.f);
            ggy[c] = ((a20-a00) + 2.f*(a21-a01) + (a22-a02)) * (1.f/6.f);
            rr[c]  = I1[idx] - I0[idx];
        }
    };

    float rho[4], gxr[4], gyr[4];
    grad4(grow, rho, gxr, gyr);
    float rho16[4]={0,0,0,0}, gx16[4]={0,0,0,0}, gy16[4]={0,0,0,0};
    if (wv == 14 && notBot) grad4(r0 + ROWS, rho16, gx16, gy16);   // halo grads in regs

    for (int k = tid; k < (ROWS+1)*W; k += NTHREADS) { (&xu0[0][0])[k]=0.f; (&xu1[0][0])[k]=0.f; }
    for (int k = tid; k < ROWS*W;     k += NTHREADS) { (&xq1[0][0])[k]=0.f; (&xq2[0][0])[k]=0.f; }
    float u0[4]={0,0,0,0}, u1[4]={0,0,0,0};
    float p1x[4]={0,0,0,0}, p1y[4]={0,0,0,0}, p2x[4]={0,0,0,0}, p2y[4]={0,0,0,0};
    __syncthreads();

    // u-step with ym term DEFERRED: caller adds th0*(wy0*q1m) afterwards.
    auto ustep_dym = [&](const float* rr, const float* ggx, const float* ggy,
                         const float* uu0, const float* uu1,
                         const float* x1, const float* q1c, const float* q1p,
                         const float* x2, const float* q2c, const float* q2p,
                         float* o0, float* o1) {
        float l1 = __shfl_up(x1[3],1), l2 = __shfl_up(x2[3],1);
        if (lane == 0) { l1 = 0.f; l2 = 0.f; }
        float r1 = __shfl_down(x1[0],1), r2 = __shfl_down(x2[0],1);
        if (lane == 63) { r1 = 0.f; r2 = 0.f; }
        const float x1m[4]={l1,x1[0],x1[1],x1[2]}, x1p[4]={x1[1],x1[2],x1[3],r1};
        const float x2m[4]={l2,x2[0],x2[1],x2[2]}, x2p[4]={x2[1],x2[2],x2[3],r2};
        #pragma unroll
        for (int c = 0; c < 4; ++c) {
            const float r  = rr[c] + ggx[c]*uu0[c] + ggy[c]*uu1[c];
            const float ng = ggx[c]*ggx[c] + ggy[c]*ggy[c] + TVEPS;
            const float f  = (fabsf(r) < tl*ng) ? (r * fastrcp(ng)) : copysignf(tl, r);
            const float d1 = wx0*x1m[c] + wx1*x1[c] + wx2*x1p[c] + wy1*q1c[c] + wy2*q1p[c];
            const float d2 = wx0*x2m[c] + wx1*x2[c] + wx2*x2p[c] + wy1*q2c[c] + wy2*q2p[c];
            o0[c] = (uu0[c] - f*ggx[c]) + th0*d1;
            o1[c] = (uu1[c] - f*ggy[c]) + th0*d2;
        }
    };
    // u-step with yp term DEFERRED: caller adds th0*(wy2*q1p) afterwards (wave 15 own row)
    auto ustep_dyp = [&](const float* rr, const float* ggx, const float* ggy,
                         const float* uu0, const float* uu1,
                         const float* x1, const float* q1m, const float* q1c,
                         const float* x2, const float* q2m, const float* q2c,
                         float* o0, float* o1) {
        float l1 = __shfl_up(x1[3],1), l2 = __shfl_up(x2[3],1);
        if (lane == 0) { l1 = 0.f; l2 = 0.f; }
        float r1 = __shfl_down(x1[0],1), r2 = __shfl_down(x2[0],1);
        if (lane == 63) { r1 = 0.f; r2 = 0.f; }
        const float x1m[4]={l1,x1[0],x1[1],x1[2]}, x1p[4]={x1[1],x1[2],x1[3],r1};
        const float x2m[4]={l2,x2[0],x2[1],x2[2]}, x2p[4]={x2[1],x2[2],x2[3],r2};
        #pragma unroll
        for (int c = 0; c < 4; ++c) {
            const float r  = rr[c] + ggx[c]*uu0[c] + ggy[c]*uu1[c];
            const float ng = ggx[c]*ggx[c] + ggy[c]*ggy[c] + TVEPS;
            const float f  = (fabsf(r) < tl*ng) ? (r * fastrcp(ng)) : copysignf(tl, r);
            const float d1 = wx0*x1m[c] + wx1*x1[c] + wx2*x1p[c] + wy0*q1m[c] + wy1*q1c[c];
            const float d2 = wx0*x2m[c] + wx1*x2[c] + wx2*x2p[c] + wy0*q2m[c] + wy1*q2c[c];
            o0[c] = (uu0[c] - f*ggx[c]) + th0*d1;
            o1[c] = (uu1[c] - f*ggy[c]) + th0*d2;
        }
    };
    // fused u-step (interior rows 1..14)
    auto ustepF = [&](const float* q1m, const float* q1p, const float* q2m, const float* q2p) {
        float l1 = __shfl_up(p1x[3],1), l2 = __shfl_up(p2x[3],1);
        if (lane == 0) { l1 = 0.f; l2 = 0.f; }
        float r1 = __shfl_down(p1x[0],1), r2 = __shfl_down(p2x[0],1);
        if (lane == 63) { r1 = 0.f; r2 = 0.f; }
        const float x1m[4]={l1,p1x[0],p1x[1],p1x[2]}, x1p[4]={p1x[1],p1x[2],p1x[3],r1};
        const float x2m[4]={l2,p2x[0],p2x[1],p2x[2]}, x2p[4]={p2x[1],p2x[2],p2x[3],r2};
        #pragma unroll
        for (int c = 0; c < 4; ++c) {
            const float r  = rho[c] + gxr[c]*u0[c] + gyr[c]*u1[c];
            const float ng = gxr[c]*gxr[c] + gyr[c]*gyr[c] + TVEPS;
            const float f  = (fabsf(r) < tl*ng) ? (r * fastrcp(ng)) : copysignf(tl, r);
            const float d1 = wx0*x1m[c] + wx1*p1x[c] + wx2*x1p[c]
                           + wy0*q1m[c] + wy1*p1y[c] + wy2*q1p[c];
            const float d2 = wx0*x2m[c] + wx1*p2x[c] + wx2*x2p[c]
                           + wy0*q2m[c] + wy1*p2y[c] + wy2*q2p[c];
            u0[c] = (u0[c] - f*gxr[c]) + th0*d1;
            u1[c] = (u1[c] - f*gyr[c]) + th0*d2;
        }
    };

    for (int it = 0; it < NUM_ITER; ++it) {
        const bool last = (it == NUM_ITER-1);
        const int tgt = FLAG_MAGIC | (it-1);

        // ---- deferred flag publication for planes stored last phase B ----
        if (it > 0 && lane == 0) {
            int* fw = flags + (size_t)(it-1) * 3 * NBLK;
            if (wv == 0 && notTop)           setflag(&fw[0*NBLK + b], tgt);   // A
            else if (wv == 1 && notTop)      setflag(&fw[1*NBLK + b], tgt);   // B
            else if (wv == ROWS-1 && notBot) setflag(&fw[2*NBLK + b], tgt);   // C
        }

        // ================= phase A: u-step (compute first, poll late) =================
        if (wv == 0) {
            bool rdy = false;
            float hym1[4]={0,0,0,0}, hym2[4]={0,0,0,0};
            const float* hp = halo + ((size_t)(it-1)*NBLK + (b-1))*HPLANES*W;
            if (it > 0 && notTop) {
                rdy = (peekflag(&flags[(size_t)(it-1)*3*NBLK + 2*NBLK + (b-1)]) == tgt);
                asm volatile("" ::: "memory");
                if (rdy) {
                    #pragma unroll
                    for (int c = 0; c < 4; ++c) {
                        hym1[c] = aload(hp + 6*W + x0 + c);
                        hym2[c] = aload(hp + 7*W + x0 + c);
                    }
                }
            }
            float pyp1[4], pyp2[4];
            LD4(pyp1, &xq1[1][x0]); LD4(pyp2, &xq2[1][x0]);
            float o0[4], o1[4];
            ustep_dym(rho, gxr, gyr, u0, u1, p1x, p1y, pyp1, p2x, p2y, pyp2, o0, o1);
            if (it > 0 && notTop && !rdy) {
                if (lane == 0) waitflag(&flags[(size_t)(it-1)*3*NBLK + 2*NBLK + (b-1)], tgt);
                #pragma unroll
                for (int c = 0; c < 4; ++c) {
                    hym1[c] = aload(hp + 6*W + x0 + c);
                    hym2[c] = aload(hp + 7*W + x0 + c);
                }
            }
            #pragma unroll
            for (int c = 0; c < 4; ++c) {
                u0[c] = o0[c] + th0*(wy0*hym1[c]);
                u1[c] = o1[c] + th0*(wy0*hym2[c]);
            }
        } else if (wv == ROWS-1) {
            bool rdy = false;
            float hyp1[4]={0,0,0,0}, hyp2[4]={0,0,0,0};
            const float* hp = halo + ((size_t)(it-1)*NBLK + (b+1))*HPLANES*W;
            if (it > 0 && notBot) {
                rdy = (peekflag(&flags[(size_t)(it-1)*3*NBLK + 0*NBLK + (b+1)]) == tgt);
                asm volatile("" ::: "memory");
                if (rdy) {
                    #pragma unroll
                    for (int c = 0; c < 4; ++c) {
                        hyp1[c] = aload(hp + 1*W + x0 + c);    // p1y(16)
                        hyp2[c] = aload(hp + 3*W + x0 + c);    // p2y(16)
                    }
                }
            }
            float pym1[4], pym2[4];
            LD4(pym1, &xq1[ROWS-2][x0]); LD4(pym2, &xq2[ROWS-2][x0]);
            float o0[4], o1[4];
            ustep_dyp(rho, gxr, gyr, u0, u1, p1x, pym1, p1y, p2x, pym2, p2y, o0, o1);
            if (it > 0 && notBot && !rdy) {
                if (lane == 0) waitflag(&flags[(size_t)(it-1)*3*NBLK + 0*NBLK + (b+1)], tgt);
                #pragma unroll
                for (int c = 0; c < 4; ++c) {
                    hyp1[c] = aload(hp + 1*W + x0 + c);
                    hyp2[c] = aload(hp + 3*W + x0 + c);
                }
            }
            #pragma unroll
            for (int c = 0; c < 4; ++c) {
                u0[c] = o0[c] + th0*(wy2*hyp1[c]);
                u1[c] = o1[c] + th0*(wy2*hyp2[c]);
            }
        } else {
            float pym1[4], pym2[4], pyp1[4], pyp2[4];
            LD4(pym1, &xq1[wv-1][x0]); LD4(pym2, &xq2[wv-1][x0]);
            LD4(pyp1, &xq1[wv+1][x0]); LD4(pyp2, &xq2[wv+1][x0]);
            ustepF(pym1, pyp1, pym2, pyp2);
        }

        if (last) {
            float* __restrict__ o0 = uout + (size_t)(2*n)   * HW + (size_t)grow * W + x0;
            float* __restrict__ o1 = uout + (size_t)(2*n+1) * HW + (size_t)grow * W + x0;
            ST4(o0, u0); ST4(o1, u1);
            break;              // uniform across block
        }
        ST4(&xu0[wv][x0], u0); ST4(&xu1[wv][x0], u1);

        // ---- wave 14: opportunistic poll + halo row-16 recompute (deferred path) ----
        if (wv == 14 && notBot) {
            float c16x1[4]={0,0,0,0}, c16x2[4]={0,0,0,0};
            float c16c1[4]={0,0,0,0}, c16c2[4]={0,0,0,0};
            float c16p1[4]={0,0,0,0}, c16p2[4]={0,0,0,0};
            if (it > 0) {
                int* fb = flags + (size_t)(it-1)*3*NBLK;
                const float* hp = halo + ((size_t)(it-1)*NBLK + (b+1))*HPLANES*W;
                const bool rdy = (peekflag(&fb[0*NBLK + (b+1)]) == tgt) &&
                                 (peekflag(&fb[1*NBLK + (b+1)]) == tgt);
                asm volatile("" ::: "memory");
                if (!rdy) {
                    if (lane < 2) waitflag(&fb[lane*NBLK + (b+1)], tgt);        // A,B(b+1)
                }
                #pragma unroll
                for (int c = 0; c < 4; ++c) {
                    c16x1[c] = aload(hp + 0*W + x0 + c);   // p1x(16)
                    c16c1[c] = aload(hp + 1*W + x0 + c);   // p1y(16)
                    c16x2[c] = aload(hp + 2*W + x0 + c);   // p2x(16)
                    c16c2[c] = aload(hp + 3*W + x0 + c);   // p2y(16)
                    c16p1[c] = aload(hp + 4*W + x0 + c);   // p1y(17)
                    c16p2[c] = aload(hp + 5*W + x0 + c);   // p2y(17)
                }
            }
            float q115[4], q215[4], u160[4], u161[4];
            LD4(q115, &xq1[ROWS-1][x0]); LD4(q215, &xq2[ROWS-1][x0]);  // prev-iter p1y/p2y(15)
            LD4(u160, &xu0[ROWS][x0]);   LD4(u161, &xu1[ROWS][x0]);    // self-maintained u(16)
            float n160[4], n161[4];
            ustep_dym(rho16, gx16, gy16, u160, u161,
                      c16x1, c16c1, c16p1, c16x2, c16c2, c16p2, n160, n161);
            #pragma unroll
            for (int c = 0; c < 4; ++c) {
                n160[c] += th0*(wy0*q115[c]);   // same late-add order as neighbor's wave 0
                n161[c] += th0*(wy0*q215[c]);
            }
            ST4(&xu0[ROWS][x0], n160); ST4(&xu1[ROWS][x0], n161);
        }
        __syncthreads();   // barrier 1: xu (incl. row 16) complete; prev-iter xq reads done

        // ================= phase B: p-step + payload stores (flags deferred) ==========
        float uy0[4], uy1[4];
        if (grow == H-1) { for (int c=0;c<4;++c){ uy0[c]=0.f; uy1[c]=0.f; } }
        else             { LD4(uy0, &xu0[wv+1][x0]); LD4(uy1, &xu1[wv+1][x0]); }
        float ur0 = __shfl_down(u0[0], 1), ur1 = __shfl_down(u1[0], 1);
        if (lane == 63) { ur0 = 0.f; ur1 = 0.f; }
        #pragma unroll
        for (int c = 0; c < 4; ++c) {
            const float uxp0 = (c < 3) ? u0[c+1] : ur0;
            const float uxp1 = (c < 3) ? u1[c+1] : ur1;
            const float g1x = uxp0 - u0[c];
            const float g1y = uy0[c] - u0[c];
            const float g2x = uxp1 - u1[c];
            const float g2y = uy1[c] - u1[c];
            const float rc1 = fastrcp(1.f + tt * (fabsf(g1x) + fabsf(g1y)));
            const float rc2 = fastrcp(1.f + tt * (fabsf(g2x) + fabsf(g2y)));
            p1x[c] = (p1x[c] + tt*g1x) * rc1;
            p1y[c] = (p1y[c] + tt*g1y) * rc1;
            p2x[c] = (p2x[c] + tt*g2x) * rc2;
            p2y[c] = (p2y[c] + tt*g2y) * rc2;
        }
        ST4(&xq1[wv][x0], p1y); ST4(&xq2[wv][x0], p2y);

        {
            float* hw = halo + ((size_t)it * NBLK + b) * HPLANES * W;
            if (wv == 0 && notTop) {
                #pragma unroll
                for (int c = 0; c < 4; ++c) {
                    astore(hw + 0*W + x0 + c, p1x[c]);
                    astore(hw + 1*W + x0 + c, p1y[c]);
                    astore(hw + 2*W + x0 + c, p2x[c]);
                    astore(hw + 3*W + x0 + c, p2y[c]);
                }
            } else if (wv == 1 && notTop) {
                #pragma unroll
                for (int c = 0; c < 4; ++c) {
                    astore(hw + 4*W + x0 + c, p1y[c]);
                    astore(hw + 5*W + x0 + c, p2y[c]);
                }
            } else if (wv == ROWS-1 && notBot) {
                #pragma unroll
                for (int c = 0; c < 4; ++c) {
                    astore(hw + 6*W + x0 + c, p1y[c]);
                    astore(hw + 7*W + x0 + c, p2y[c]);
                }
            }
        }
        __syncthreads();   // barrier 2: xq writes visible for next iter's phase A
    }
}

// ---------------- fallback path (round-1, known good) ----------------

__global__ void precompute_kernel(const float* __restrict__ x,
                                  float* __restrict__ u,
                                  float* __restrict__ ws) {
    const int row = blockIdx.x;
    const int n = row / H, y = row % H;
    const int xx = threadIdx.x;
    const int idx = y * W + xx;
    const float* __restrict__ I0 = x + (size_t)n * HW;
    const float* __restrict__ I1 = x + (size_t)(NB + n) * HW;
    float* __restrict__ p1  = ws;
    float* __restrict__ p2  = ws + (size_t)2 * NB * HW;
    float* __restrict__ rho = ws + (size_t)4 * NB * HW;
    float* __restrict__ gxp = ws + (size_t)5 * NB * HW;
    float* __restrict__ gyp = ws + (size_t)6 * NB * HW;
    const float i1c = I1[idx];
    const bool xm = xx > 0, xp = xx < W - 1, ym = y > 0, yp = y < H - 1;
    float a00=0.f,a01=0.f,a02=0.f,a10=0.f,a12=0.f,a20=0.f,a21=0.f,a22=0.f;
    if (ym) { a01 = I1[idx-W]; if (xm) a00 = I1[idx-W-1]; if (xp) a02 = I1[idx-W+1]; }
    if (xm) a10 = I1[idx-1];
    if (xp) a12 = I1[idx+1];
    if (yp) { a21 = I1[idx+W]; if (xm) a20 = I1[idx+W-1]; if (xp) a22 = I1[idx+W+1]; }
    const float gxv = ((a02-a00) + 2.f*(a12-a10) + (a22-a20)) * (1.f/6.f);
    const float gyv = ((a20-a00) + 2.f*(a21-a01) + (a22-a02)) * (1.f/6.f);
    const size_t np = (size_t)n * HW;
    rho[np+idx] = i1c - I0[idx];
    gxp[np+idx] = gxv;
    gyp[np+idx] = gyv;
    u[(size_t)(2*n)*HW + idx] = 0.f;   u[(size_t)(2*n+1)*HW + idx] = 0.f;
    p1[(size_t)(2*n)*HW + idx] = 0.f;  p1[(size_t)(2*n+1)*HW + idx] = 0.f;
    p2[(size_t)(2*n)*HW + idx] = 0.f;  p2[(size_t)(2*n+1)*HW + idx] = 0.f;
}

__global__ void u_kernel(const float* __restrict__ ws,
                         float* __restrict__ u,
                         const float* __restrict__ lam,
                         const float* __restrict__ theta,
                         const float* __restrict__ wxv,
                         const float* __restrict__ wyv) {
    const int row = blockIdx.x;
    const int n = row / H, y = row % H;
    const int xx = threadIdx.x;
    const int idx = y * W + xx;
    const size_t np = (size_t)n * HW;
    const float* __restrict__ p1  = ws;
    const float* __restrict__ p2  = ws + (size_t)2 * NB * HW;
    const float* __restrict__ rho_c = ws + (size_t)4 * NB * HW;
    const float* __restrict__ gxp = ws + (size_t)5 * NB * HW;
    const float* __restrict__ gyp = ws + (size_t)6 * NB * HW;
    const float th0 = theta[0];
    const float tl = th0 * lam[0];
    const float wx0 = wxv[0], wx1 = wxv[1], wx2 = wxv[2];
    const float wy0 = wyv[0], wy1 = wyv[1], wy2 = wyv[2];
    const float gx = gxp[np+idx];
    const float gy = gyp[np+idx];
    float* __restrict__ u0p = u + (size_t)(2*n)*HW;
    float* __restrict__ u1p = u + (size_t)(2*n+1)*HW;
    const float u0 = u0p[idx], u1 = u1p[idx];
    const float rho = rho_c[np+idx] + gx*u0 + gy*u1;
    const float ng = gx*gx + gy*gy + TVEPS;
    const float th = tl * ng;
    float s0, s1;
    if (fabsf(rho) < th) { const float d = rho/ng; s0 = d*gx; s1 = d*gy; }
    else { const float sg = (rho > 0.f) ? 1.f : ((rho < 0.f) ? -1.f : 0.f);
           s0 = tl*gx*sg; s1 = tl*gy*sg; }
    const float v0 = u0 - s0, v1 = u1 - s1;
    const float* __restrict__ p1xp = p1 + (size_t)(2*n)*HW;
    const float* __restrict__ p1yp = p1 + (size_t)(2*n+1)*HW;
    const float* __restrict__ p2xp = p2 + (size_t)(2*n)*HW;
    const float* __restrict__ p2yp = p2 + (size_t)(2*n+1)*HW;
    float d1 = wx1*p1xp[idx] + wy1*p1yp[idx];
    float d2 = wx1*p2xp[idx] + wy1*p2yp[idx];
    if (xx > 0)     { d1 += wx0*p1xp[idx-1]; d2 += wx0*p2xp[idx-1]; }
    if (xx < W-1)   { d1 += wx2*p1xp[idx+1]; d2 += wx2*p2xp[idx+1]; }
    if (y > 0)      { d1 += wy0*p1yp[idx-W]; d2 += wy0*p2yp[idx-W]; }
    if (y < H-1)    { d1 += wy2*p1yp[idx+W]; d2 += wy2*p2yp[idx+W]; }
    u0p[idx] = v0 + th0*d1;
    u1p[idx] = v1 + th0*d2;
}

__global__ void p_kernel(const float* __restrict__ u,
                         float* __restrict__ ws,
                         const float* __restrict__ tau,
                         const float* __restrict__ theta) {
    const int row = blockIdx.x;
    const int n = row / H, y = row % H;
    const int xx = threadIdx.x;
    const int idx = y * W + xx;
    float* __restrict__ p1 = ws;
    float* __restrict__ p2 = ws + (size_t)2 * NB * HW;
    const float tt = tau[0] / theta[0];
    const float* __restrict__ u0p = u + (size_t)(2*n)*HW;
    const float* __restrict__ u1p = u + (size_t)(2*n+1)*HW;
    const float c0 = u0p[idx];
    const float g1x = ((xx < W-1) ? u0p[idx+1] : 0.f) - c0;
    const float g1y = ((y < H-1) ? u0p[idx+W] : 0.f) - c0;
    const float c1 = u1p[idx];
    const float g2x = ((xx < W-1) ? u1p[idx+1] : 0.f) - c1;
    const float g2y = ((y < H-1) ? u1p[idx+W] : 0.f) - c1;
    float* __restrict__ p1xp = p1 + (size_t)(2*n)*HW;
    float* __restrict__ p1yp = p1 + (size_t)(2*n+1)*HW;
    float* __restrict__ p2xp = p2 + (size_t)(2*n)*HW;
    float* __restrict__ p2yp = p2 + (size_t)(2*n+1)*HW;
    const float den1 = 1.f + tt * (fabsf(g1x) + fabsf(g1y));
    p1xp[idx] = (p1xp[idx] + tt*g1x) / den1;
    p1yp[idx] = (p1yp[idx] + tt*g1y) / den1;
    const float den2 = 1.f + tt * (fabsf(g2x) + fabsf(g2y));
    p2xp[idx] = (p2xp[idx] + tt*g2x) / den2;
    p2yp[idx] = (p2yp[idx] + tt*g2y) / den2;
}

extern "C" void kernel_launch(void* const* d_in, const int* in_sizes, int n_in,
                              void* d_out, int out_size, void* d_ws, size_t ws_size,
                              hipStream_t stream) {
    const float* x     = (const float*)d_in[0];
    const float* lam   = (const float*)d_in[1];
    const float* tau   = (const float*)d_in[2];
    const float* theta = (const float*)d_in[3];
    const float* wxv   = (const float*)d_in[4];
    const float* wyv   = (const float*)d_in[5];
    float* u = (float*)d_out;

    const size_t halo_floats = (size_t)(NUM_ITER-1) * NBLK * HPLANES * W;
    const size_t need = halo_floats * sizeof(float)
                      + (size_t)(NUM_ITER-1) * 3 * NBLK * sizeof(int);

    if (ws_size >= need) {
        float* halo = (float*)d_ws;
        int* flags = (int*)((char*)d_ws + halo_floats * sizeof(float));
        void* args[] = { (void*)&x, (void*)&lam, (void*)&tau, (void*)&theta,
                         (void*)&wxv, (void*)&wyv, (void*)&u, (void*)&halo, (void*)&flags };
        hipLaunchCooperativeKernel((void*)tvl1_xcd_kernel, dim3(NBLK), dim3(NTHREADS),
                                   args, 0, stream);
    } else {
        float* ws = (float*)d_ws;
        const dim3 grid(NB * H);
        const dim3 block(W);
        precompute_kernel<<<grid, block, 0, stream>>>(x, u, ws);
        for (int it = 0; it < NUM_ITER; ++it) {
            u_kernel<<<grid, block, 0, stream>>>(ws, u, lam, theta, wxv, wyv);
            p_kernel<<<grid, block, 0, stream>>>(u, ws, tau, theta);
        }
    }
}

// Round 15
// 102.118 us; speedup vs baseline: 1.2019x; 1.2019x over previous
//
#include <hip/hip_runtime.h>

#define W 256
#define H 256
#define HW (W*H)
#define NB 12
#define ROWS 16
#define BPI (H/ROWS)            // 16 strips per image
#define NBLK (NB*BPI)           // 192 blocks (1/CU, co-resident via cooperative launch)
#define NTHREADS 1024           // 16 waves; wave = row, lane = 4-px chunk
#define NUM_ITER 20
#define TVEPS 1e-8f
#define HPLANES 8
#define FLAG_MAGIC 0x5A170000

// d_ws layout: halo[NUM_ITER-1][NBLK][HPLANES][W] floats, then flags[NUM_ITER-1][3][NBLK].
// planes: 0:p1x(r0) 1:p1y(r0) 2:p2x(r0) 3:p2y(r0) 4:p1y(r1) 5:p2y(r1) 6:p1y(r15) 7:p2y(r15)
// flags : 0=A (wave0, planes0-3) 1=B (wave1, planes4-5) 2=C (wave15, planes6-7)
// R11 schedule + (1) flag publication DEFERRED to top of next iteration and
// (2) opportunistic non-blocking flag peek at phase-A start. Identity block mapping:
// cooperative dispatch places consecutive blockIdx contiguously per XCD (R14's remap
// regression proved it), so b±1 handshakes are already same-XCD L2-local.

__device__ __forceinline__ float aload(const float* p) {
    return __hip_atomic_load(p, __ATOMIC_RELAXED, __HIP_MEMORY_SCOPE_AGENT);
}
__device__ __forceinline__ void astore(float* p, float v) {
    __hip_atomic_store(p, v, __ATOMIC_RELAXED, __HIP_MEMORY_SCOPE_AGENT);
}
__device__ __forceinline__ void waitflag(const int* f, int tgt) {
    while (__hip_atomic_load(f, __ATOMIC_RELAXED, __HIP_MEMORY_SCOPE_AGENT) != tgt)
        __builtin_amdgcn_s_sleep(1);
    asm volatile("" ::: "memory");
}
__device__ __forceinline__ int peekflag(const int* f) {
    return __hip_atomic_load(f, __ATOMIC_RELAXED, __HIP_MEMORY_SCOPE_AGENT);
}
__device__ __forceinline__ void setflag(int* f, int tgt) {
    asm volatile("s_waitcnt vmcnt(0)" ::: "memory");   // data-before-flag; drain ~0 (deferred)
    __hip_atomic_store(f, tgt, __ATOMIC_RELAXED, __HIP_MEMORY_SCOPE_AGENT);
}
__device__ __forceinline__ float fastrcp(float x) { return __builtin_amdgcn_rcpf(x); }

#define LD4(dst, ptr) { const float4 _t = *reinterpret_cast<const float4*>(ptr); \
                        dst[0]=_t.x; dst[1]=_t.y; dst[2]=_t.z; dst[3]=_t.w; }
#define ST4(ptr, src) { float4 _t; _t.x=src[0]; _t.y=src[1]; _t.z=src[2]; _t.w=src[3]; \
                        *reinterpret_cast<float4*>(ptr) = _t; }

__global__ __launch_bounds__(NTHREADS, 1) void tvl1_opp_kernel(
    const float* __restrict__ xin,
    const float* __restrict__ lam,
    const float* __restrict__ tau,
    const float* __restrict__ theta,
    const float* __restrict__ wxv,
    const float* __restrict__ wyv,
    float* __restrict__ uout,
    float* __restrict__ halo,
    int* __restrict__ flags)
{
    __shared__ float xu0[ROWS+1][W];   // u rows 0..16 (row16 maintained by wave 14)
    __shared__ float xu1[ROWS+1][W];
    __shared__ float xq1[ROWS][W];     // p1y rows 0..15
    __shared__ float xq2[ROWS][W];

    const int tid  = threadIdx.x;
    const int lane = tid & 63;
    const int wv   = tid >> 6;          // row within strip, 0..15
    const int x0   = lane << 2;
    const int b    = blockIdx.x;
    const int n    = b / BPI, bi = b % BPI;
    const int r0   = bi * ROWS;
    const int grow = r0 + wv;
    const bool notTop = (bi > 0), notBot = (bi < BPI-1);

    const float th0 = theta[0];
    const float tl  = th0 * lam[0];
    const float tt  = tau[0] / th0;
    const float wx0 = wxv[0], wx1 = wxv[1], wx2 = wxv[2];
    const float wy0 = wyv[0], wy1 = wyv[1], wy2 = wyv[2];

    const float* __restrict__ I0 = xin + (size_t)n * HW;
    const float* __restrict__ I1 = xin + (size_t)(NB + n) * HW;

    auto grad4 = [&](int row, float* rr, float* ggx, float* ggy) {
        #pragma unroll
        for (int c = 0; c < 4; ++c) {
            const int xc = x0 + c;
            const int idx = row * W + xc;
            const bool xm = xc > 0, xp = xc < W-1, ym = row > 0, yp = row < H-1;
            float a00=0.f,a01=0.f,a02=0.f,a10=0.f,a12=0.f,a20=0.f,a21=0.f,a22=0.f;
            if (ym) { a01=I1[idx-W]; if (xm) a00=I1[idx-W-1]; if (xp) a02=I1[idx-W+1]; }
            if (xm) a10=I1[idx-1];
            if (xp) a12=I1[idx+1];
            if (yp) { a21=I1[idx+W]; if (xm) a20=I1[idx+W-1]; if (xp) a22=I1[idx+W+1]; }
            ggx[c] = ((a02-a00) + 2.f*(a12-a10) + (a22-a20)) * (1.f/6.f);
            ggy[c] = ((a20-a00) + 2.f*(a21-a01) + (a22-a02)) * (1.f/6.f);
            rr[c]  = I1[idx] - I0[idx];
        }
    };

    float rho[4], gxr[4], gyr[4];
    grad4(grow, rho, gxr, gyr);
    float rho16[4]={0,0,0,0}, gx16[4]={0,0,0,0}, gy16[4]={0,0,0,0};
    if (wv == 14 && notBot) grad4(r0 + ROWS, rho16, gx16, gy16);   // halo grads in regs

    for (int k = tid; k < (ROWS+1)*W; k += NTHREADS) { (&xu0[0][0])[k]=0.f; (&xu1[0][0])[k]=0.f; }
    for (int k = tid; k < ROWS*W;     k += NTHREADS) { (&xq1[0][0])[k]=0.f; (&xq2[0][0])[k]=0.f; }
    float u0[4]={0,0,0,0}, u1[4]={0,0,0,0};
    float p1x[4]={0,0,0,0}, p1y[4]={0,0,0,0}, p2x[4]={0,0,0,0}, p2y[4]={0,0,0,0};
    __syncthreads();

    // u-step with ym term DEFERRED: caller adds th0*(wy0*q1m) afterwards.
    auto ustep_dym = [&](const float* rr, const float* ggx, const float* ggy,
                         const float* uu0, const float* uu1,
                         const float* x1, const float* q1c, const float* q1p,
                         const float* x2, const float* q2c, const float* q2p,
                         float* o0, float* o1) {
        float l1 = __shfl_up(x1[3],1), l2 = __shfl_up(x2[3],1);
        if (lane == 0) { l1 = 0.f; l2 = 0.f; }
        float r1 = __shfl_down(x1[0],1), r2 = __shfl_down(x2[0],1);
        if (lane == 63) { r1 = 0.f; r2 = 0.f; }
        const float x1m[4]={l1,x1[0],x1[1],x1[2]}, x1p[4]={x1[1],x1[2],x1[3],r1};
        const float x2m[4]={l2,x2[0],x2[1],x2[2]}, x2p[4]={x2[1],x2[2],x2[3],r2};
        #pragma unroll
        for (int c = 0; c < 4; ++c) {
            const float r  = rr[c] + ggx[c]*uu0[c] + ggy[c]*uu1[c];
            const float ng = ggx[c]*ggx[c] + ggy[c]*ggy[c] + TVEPS;
            const float f  = (fabsf(r) < tl*ng) ? (r * fastrcp(ng)) : copysignf(tl, r);
            const float d1 = wx0*x1m[c] + wx1*x1[c] + wx2*x1p[c] + wy1*q1c[c] + wy2*q1p[c];
            const float d2 = wx0*x2m[c] + wx1*x2[c] + wx2*x2p[c] + wy1*q2c[c] + wy2*q2p[c];
            o0[c] = (uu0[c] - f*ggx[c]) + th0*d1;
            o1[c] = (uu1[c] - f*ggy[c]) + th0*d2;
        }
    };
    // u-step with yp term DEFERRED: caller adds th0*(wy2*q1p) afterwards (wave 15 own row)
    auto ustep_dyp = [&](const float* rr, const float* ggx, const float* ggy,
                         const float* uu0, const float* uu1,
                         const float* x1, const float* q1m, const float* q1c,
                         const float* x2, const float* q2m, const float* q2c,
                         float* o0, float* o1) {
        float l1 = __shfl_up(x1[3],1), l2 = __shfl_up(x2[3],1);
        if (lane == 0) { l1 = 0.f; l2 = 0.f; }
        float r1 = __shfl_down(x1[0],1), r2 = __shfl_down(x2[0],1);
        if (lane == 63) { r1 = 0.f; r2 = 0.f; }
        const float x1m[4]={l1,x1[0],x1[1],x1[2]}, x1p[4]={x1[1],x1[2],x1[3],r1};
        const float x2m[4]={l2,x2[0],x2[1],x2[2]}, x2p[4]={x2[1],x2[2],x2[3],r2};
        #pragma unroll
        for (int c = 0; c < 4; ++c) {
            const float r  = rr[c] + ggx[c]*uu0[c] + ggy[c]*uu1[c];
            const float ng = ggx[c]*ggx[c] + ggy[c]*ggy[c] + TVEPS;
            const float f  = (fabsf(r) < tl*ng) ? (r * fastrcp(ng)) : copysignf(tl, r);
            const float d1 = wx0*x1m[c] + wx1*x1[c] + wx2*x1p[c] + wy0*q1m[c] + wy1*q1c[c];
            const float d2 = wx0*x2m[c] + wx1*x2[c] + wx2*x2p[c] + wy0*q2m[c] + wy1*q2c[c];
            o0[c] = (uu0[c] - f*ggx[c]) + th0*d1;
            o1[c] = (uu1[c] - f*ggy[c]) + th0*d2;
        }
    };
    // fused u-step (interior rows 1..14)
    auto ustepF = [&](const float* q1m, const float* q1p, const float* q2m, const float* q2p) {
        float l1 = __shfl_up(p1x[3],1), l2 = __shfl_up(p2x[3],1);
        if (lane == 0) { l1 = 0.f; l2 = 0.f; }
        float r1 = __shfl_down(p1x[0],1), r2 = __shfl_down(p2x[0],1);
        if (lane == 63) { r1 = 0.f; r2 = 0.f; }
        const float x1m[4]={l1,p1x[0],p1x[1],p1x[2]}, x1p[4]={p1x[1],p1x[2],p1x[3],r1};
        const float x2m[4]={l2,p2x[0],p2x[1],p2x[2]}, x2p[4]={p2x[1],p2x[2],p2x[3],r2};
        #pragma unroll
        for (int c = 0; c < 4; ++c) {
            const float r  = rho[c] + gxr[c]*u0[c] + gyr[c]*u1[c];
            const float ng = gxr[c]*gxr[c] + gyr[c]*gyr[c] + TVEPS;
            const float f  = (fabsf(r) < tl*ng) ? (r * fastrcp(ng)) : copysignf(tl, r);
            const float d1 = wx0*x1m[c] + wx1*p1x[c] + wx2*x1p[c]
                           + wy0*q1m[c] + wy1*p1y[c] + wy2*q1p[c];
            const float d2 = wx0*x2m[c] + wx1*p2x[c] + wx2*x2p[c]
                           + wy0*q2m[c] + wy1*p2y[c] + wy2*q2p[c];
            u0[c] = (u0[c] - f*gxr[c]) + th0*d1;
            u1[c] = (u1[c] - f*gyr[c]) + th0*d2;
        }
    };

    for (int it = 0; it < NUM_ITER; ++it) {
        const bool last = (it == NUM_ITER-1);
        const int tgt = FLAG_MAGIC | (it-1);

        // ---- (1) deferred flag publication for planes stored last phase B ----
        if (it > 0 && lane == 0) {
            int* fw = flags + (size_t)(it-1) * 3 * NBLK;
            if (wv == 0 && notTop)           setflag(&fw[0*NBLK + b], tgt);   // A
            else if (wv == 1 && notTop)      setflag(&fw[1*NBLK + b], tgt);   // B
            else if (wv == ROWS-1 && notBot) setflag(&fw[2*NBLK + b], tgt);   // C
        }

        // ================= phase A: u-step (compute first, poll late) =================
        if (wv == 0) {
            // (2) opportunistic early poll of C(b-1)
            bool rdy = false;
            float hym1[4]={0,0,0,0}, hym2[4]={0,0,0,0};
            const float* hp = halo + ((size_t)(it-1)*NBLK + (b-1))*HPLANES*W;
            if (it > 0 && notTop) {
                rdy = (peekflag(&flags[(size_t)(it-1)*3*NBLK + 2*NBLK + (b-1)]) == tgt);
                asm volatile("" ::: "memory");
                if (rdy) {
                    #pragma unroll
                    for (int c = 0; c < 4; ++c) {
                        hym1[c] = aload(hp + 6*W + x0 + c);
                        hym2[c] = aload(hp + 7*W + x0 + c);
                    }
                }
            }
            float pyp1[4], pyp2[4];
            LD4(pyp1, &xq1[1][x0]); LD4(pyp2, &xq2[1][x0]);
            float o0[4], o1[4];
            ustep_dym(rho, gxr, gyr, u0, u1, p1x, p1y, pyp1, p2x, p2y, pyp2, o0, o1);
            if (it > 0 && notTop && !rdy) {
                if (lane == 0) waitflag(&flags[(size_t)(it-1)*3*NBLK + 2*NBLK + (b-1)], tgt);
                #pragma unroll
                for (int c = 0; c < 4; ++c) {
                    hym1[c] = aload(hp + 6*W + x0 + c);
                    hym2[c] = aload(hp + 7*W + x0 + c);
                }
            }
            #pragma unroll
            for (int c = 0; c < 4; ++c) {
                u0[c] = o0[c] + th0*(wy0*hym1[c]);
                u1[c] = o1[c] + th0*(wy0*hym2[c]);
            }
        } else if (wv == ROWS-1) {
            bool rdy = false;
            float hyp1[4]={0,0,0,0}, hyp2[4]={0,0,0,0};
            const float* hp = halo + ((size_t)(it-1)*NBLK + (b+1))*HPLANES*W;
            if (it > 0 && notBot) {
                rdy = (peekflag(&flags[(size_t)(it-1)*3*NBLK + 0*NBLK + (b+1)]) == tgt);
                asm volatile("" ::: "memory");
                if (rdy) {
                    #pragma unroll
                    for (int c = 0; c < 4; ++c) {
                        hyp1[c] = aload(hp + 1*W + x0 + c);    // p1y(16)
                        hyp2[c] = aload(hp + 3*W + x0 + c);    // p2y(16)
                    }
                }
            }
            float pym1[4], pym2[4];
            LD4(pym1, &xq1[ROWS-2][x0]); LD4(pym2, &xq2[ROWS-2][x0]);
            float o0[4], o1[4];
            ustep_dyp(rho, gxr, gyr, u0, u1, p1x, pym1, p1y, p2x, pym2, p2y, o0, o1);
            if (it > 0 && notBot && !rdy) {
                if (lane == 0) waitflag(&flags[(size_t)(it-1)*3*NBLK + 0*NBLK + (b+1)], tgt);
                #pragma unroll
                for (int c = 0; c < 4; ++c) {
                    hyp1[c] = aload(hp + 1*W + x0 + c);
                    hyp2[c] = aload(hp + 3*W + x0 + c);
                }
            }
            #pragma unroll
            for (int c = 0; c < 4; ++c) {
                u0[c] = o0[c] + th0*(wy2*hyp1[c]);
                u1[c] = o1[c] + th0*(wy2*hyp2[c]);
            }
        } else {
            float pym1[4], pym2[4], pyp1[4], pyp2[4];
            LD4(pym1, &xq1[wv-1][x0]); LD4(pym2, &xq2[wv-1][x0]);
            LD4(pyp1, &xq1[wv+1][x0]); LD4(pyp2, &xq2[wv+1][x0]);
            ustepF(pym1, pyp1, pym2, pyp2);
        }

        if (last) {
            float* __restrict__ o0 = uout + (size_t)(2*n)   * HW + (size_t)grow * W + x0;
            float* __restrict__ o1 = uout + (size_t)(2*n+1) * HW + (size_t)grow * W + x0;
            ST4(o0, u0); ST4(o1, u1);
            break;              // uniform across block
        }
        ST4(&xu0[wv][x0], u0); ST4(&xu1[wv][x0], u1);

        // ---- wave 14: opportunistic poll + halo row-16 recompute (deferred path) ----
        if (wv == 14 && notBot) {
            float c16x1[4]={0,0,0,0}, c16x2[4]={0,0,0,0};
            float c16c1[4]={0,0,0,0}, c16c2[4]={0,0,0,0};
            float c16p1[4]={0,0,0,0}, c16p2[4]={0,0,0,0};
            if (it > 0) {
                int* fb = flags + (size_t)(it-1)*3*NBLK;
                const float* hp = halo + ((size_t)(it-1)*NBLK + (b+1))*HPLANES*W;
                const bool rdy = (peekflag(&fb[0*NBLK + (b+1)]) == tgt) &&
                                 (peekflag(&fb[1*NBLK + (b+1)]) == tgt);
                asm volatile("" ::: "memory");
                if (!rdy) {
                    if (lane < 2) waitflag(&fb[lane*NBLK + (b+1)], tgt);        // A,B(b+1)
                }
                #pragma unroll
                for (int c = 0; c < 4; ++c) {
                    c16x1[c] = aload(hp + 0*W + x0 + c);   // p1x(16)
                    c16c1[c] = aload(hp + 1*W + x0 + c);   // p1y(16)
                    c16x2[c] = aload(hp + 2*W + x0 + c);   // p2x(16)
                    c16c2[c] = aload(hp + 3*W + x0 + c);   // p2y(16)
                    c16p1[c] = aload(hp + 4*W + x0 + c);   // p1y(17)
                    c16p2[c] = aload(hp + 5*W + x0 + c);   // p2y(17)
                }
            }
            float q115[4], q215[4], u160[4], u161[4];
            LD4(q115, &xq1[ROWS-1][x0]); LD4(q215, &xq2[ROWS-1][x0]);  // prev-iter p1y/p2y(15)
            LD4(u160, &xu0[ROWS][x0]);   LD4(u161, &xu1[ROWS][x0]);    // self-maintained u(16)
            float n160[4], n161[4];
            ustep_dym(rho16, gx16, gy16, u160, u161,
                      c16x1, c16c1, c16p1, c16x2, c16c2, c16p2, n160, n161);
            #pragma unroll
            for (int c = 0; c < 4; ++c) {
                n160[c] += th0*(wy0*q115[c]);   // same late-add order as neighbor's wave 0
                n161[c] += th0*(wy0*q215[c]);
            }
            ST4(&xu0[ROWS][x0], n160); ST4(&xu1[ROWS][x0], n161);
        }
        __syncthreads();   // barrier 1: xu (incl. row 16) complete; prev-iter xq reads done

        // ================= phase B: p-step + payload stores (flags deferred) ==========
        float uy0[4], uy1[4];
        if (grow == H-1) { for (int c=0;c<4;++c){ uy0[c]=0.f; uy1[c]=0.f; } }
        else             { LD4(uy0, &xu0[wv+1][x0]); LD4(uy1, &xu1[wv+1][x0]); }
        float ur0 = __shfl_down(u0[0], 1), ur1 = __shfl_down(u1[0], 1);
        if (lane == 63) { ur0 = 0.f; ur1 = 0.f; }
        #pragma unroll
        for (int c = 0; c < 4; ++c) {
            const float uxp0 = (c < 3) ? u0[c+1] : ur0;
            const float uxp1 = (c < 3) ? u1[c+1] : ur1;
            const float g1x = uxp0 - u0[c];
            const float g1y = uy0[c] - u0[c];
            const float g2x = uxp1 - u1[c];
            const float g2y = uy1[c] - u1[c];
            const float rc1 = fastrcp(1.f + tt * (fabsf(g1x) + fabsf(g1y)));
            const float rc2 = fastrcp(1.f + tt * (fabsf(g2x) + fabsf(g2y)));
            p1x[c] = (p1x[c] + tt*g1x) * rc1;
            p1y[c] = (p1y[c] + tt*g1y) * rc1;
            p2x[c] = (p2x[c] + tt*g2x) * rc2;
            p2y[c] = (p2y[c] + tt*g2y) * rc2;
        }
        ST4(&xq1[wv][x0], p1y); ST4(&xq2[wv][x0], p2y);

        {
            float* hw = halo + ((size_t)it * NBLK + b) * HPLANES * W;
            if (wv == 0 && notTop) {
                #pragma unroll
                for (int c = 0; c < 4; ++c) {
                    astore(hw + 0*W + x0 + c, p1x[c]);
                    astore(hw + 1*W + x0 + c, p1y[c]);
                    astore(hw + 2*W + x0 + c, p2x[c]);
                    astore(hw + 3*W + x0 + c, p2y[c]);
                }
            } else if (wv == 1 && notTop) {
                #pragma unroll
                for (int c = 0; c < 4; ++c) {
                    astore(hw + 4*W + x0 + c, p1y[c]);
                    astore(hw + 5*W + x0 + c, p2y[c]);
                }
            } else if (wv == ROWS-1 && notBot) {
                #pragma unroll
                for (int c = 0; c < 4; ++c) {
                    astore(hw + 6*W + x0 + c, p1y[c]);
                    astore(hw + 7*W + x0 + c, p2y[c]);
                }
            }
        }
        __syncthreads();   // barrier 2: xq writes visible for next iter's phase A
    }
}

// ---------------- fallback path (round-1, known good) ----------------

__global__ void precompute_kernel(const float* __restrict__ x,
                                  float* __restrict__ u,
                                  float* __restrict__ ws) {
    const int row = blockIdx.x;
    const int n = row / H, y = row % H;
    const int xx = threadIdx.x;
    const int idx = y * W + xx;
    const float* __restrict__ I0 = x + (size_t)n * HW;
    const float* __restrict__ I1 = x + (size_t)(NB + n) * HW;
    float* __restrict__ p1  = ws;
    float* __restrict__ p2  = ws + (size_t)2 * NB * HW;
    float* __restrict__ rho = ws + (size_t)4 * NB * HW;
    float* __restrict__ gxp = ws + (size_t)5 * NB * HW;
    float* __restrict__ gyp = ws + (size_t)6 * NB * HW;
    const float i1c = I1[idx];
    const bool xm = xx > 0, xp = xx < W - 1, ym = y > 0, yp = y < H - 1;
    float a00=0.f,a01=0.f,a02=0.f,a10=0.f,a12=0.f,a20=0.f,a21=0.f,a22=0.f;
    if (ym) { a01 = I1[idx-W]; if (xm) a00 = I1[idx-W-1]; if (xp) a02 = I1[idx-W+1]; }
    if (xm) a10 = I1[idx-1];
    if (xp) a12 = I1[idx+1];
    if (yp) { a21 = I1[idx+W]; if (xm) a20 = I1[idx+W-1]; if (xp) a22 = I1[idx+W+1]; }
    const float gxv = ((a02-a00) + 2.f*(a12-a10) + (a22-a20)) * (1.f/6.f);
    const float gyv = ((a20-a00) + 2.f*(a21-a01) + (a22-a02)) * (1.f/6.f);
    const size_t np = (size_t)n * HW;
    rho[np+idx] = i1c - I0[idx];
    gxp[np+idx] = gxv;
    gyp[np+idx] = gyv;
    u[(size_t)(2*n)*HW + idx] = 0.f;   u[(size_t)(2*n+1)*HW + idx] = 0.f;
    p1[(size_t)(2*n)*HW + idx] = 0.f;  p1[(size_t)(2*n+1)*HW + idx] = 0.f;
    p2[(size_t)(2*n)*HW + idx] = 0.f;  p2[(size_t)(2*n+1)*HW + idx] = 0.f;
}

__global__ void u_kernel(const float* __restrict__ ws,
                         float* __restrict__ u,
                         const float* __restrict__ lam,
                         const float* __restrict__ theta,
                         const float* __restrict__ wxv,
                         const float* __restrict__ wyv) {
    const int row = blockIdx.x;
    const int n = row / H, y = row % H;
    const int xx = threadIdx.x;
    const int idx = y * W + xx;
    const size_t np = (size_t)n * HW;
    const float* __restrict__ p1  = ws;
    const float* __restrict__ p2  = ws + (size_t)2 * NB * HW;
    const float* __restrict__ rho_c = ws + (size_t)4 * NB * HW;
    const float* __restrict__ gxp = ws + (size_t)5 * NB * HW;
    const float* __restrict__ gyp = ws + (size_t)6 * NB * HW;
    const float th0 = theta[0];
    const float tl = th0 * lam[0];
    const float wx0 = wxv[0], wx1 = wxv[1], wx2 = wxv[2];
    const float wy0 = wyv[0], wy1 = wyv[1], wy2 = wyv[2];
    const float gx = gxp[np+idx];
    const float gy = gyp[np+idx];
    float* __restrict__ u0p = u + (size_t)(2*n)*HW;
    float* __restrict__ u1p = u + (size_t)(2*n+1)*HW;
    const float u0 = u0p[idx], u1 = u1p[idx];
    const float rho = rho_c[np+idx] + gx*u0 + gy*u1;
    const float ng = gx*gx + gy*gy + TVEPS;
    const float th = tl * ng;
    float s0, s1;
    if (fabsf(rho) < th) { const float d = rho/ng; s0 = d*gx; s1 = d*gy; }
    else { const float sg = (rho > 0.f) ? 1.f : ((rho < 0.f) ? -1.f : 0.f);
           s0 = tl*gx*sg; s1 = tl*gy*sg; }
    const float v0 = u0 - s0, v1 = u1 - s1;
    const float* __restrict__ p1xp = p1 + (size_t)(2*n)*HW;
    const float* __restrict__ p1yp = p1 + (size_t)(2*n+1)*HW;
    const float* __restrict__ p2xp = p2 + (size_t)(2*n)*HW;
    const float* __restrict__ p2yp = p2 + (size_t)(2*n+1)*HW;
    float d1 = wx1*p1xp[idx] + wy1*p1yp[idx];
    float d2 = wx1*p2xp[idx] + wy1*p2yp[idx];
    if (xx > 0)     { d1 += wx0*p1xp[idx-1]; d2 += wx0*p2xp[idx-1]; }
    if (xx < W-1)   { d1 += wx2*p1xp[idx+1]; d2 += wx2*p2xp[idx+1]; }
    if (y > 0)      { d1 += wy0*p1yp[idx-W]; d2 += wy0*p2yp[idx-W]; }
    if (y < H-1)    { d1 += wy2*p1yp[idx+W]; d2 += wy2*p2yp[idx+W]; }
    u0p[idx] = v0 + th0*d1;
    u1p[idx] = v1 + th0*d2;
}

__global__ void p_kernel(const float* __restrict__ u,
                         float* __restrict__ ws,
                         const float* __restrict__ tau,
                         const float* __restrict__ theta) {
    const int row = blockIdx.x;
    const int n = row / H, y = row % H;
    const int xx = threadIdx.x;
    const int idx = y * W + xx;
    float* __restrict__ p1 = ws;
    float* __restrict__ p2 = ws + (size_t)2 * NB * HW;
    const float tt = tau[0] / theta[0];
    const float* __restrict__ u0p = u + (size_t)(2*n)*HW;
    const float* __restrict__ u1p = u + (size_t)(2*n+1)*HW;
    const float c0 = u0p[idx];
    const float g1x = ((xx < W-1) ? u0p[idx+1] : 0.f) - c0;
    const float g1y = ((y < H-1) ? u0p[idx+W] : 0.f) - c0;
    const float c1 = u1p[idx];
    const float g2x = ((xx < W-1) ? u1p[idx+1] : 0.f) - c1;
    const float g2y = ((y < H-1) ? u1p[idx+W] : 0.f) - c1;
    float* __restrict__ p1xp = p1 + (size_t)(2*n)*HW;
    float* __restrict__ p1yp = p1 + (size_t)(2*n+1)*HW;
    float* __restrict__ p2xp = p2 + (size_t)(2*n)*HW;
    float* __restrict__ p2yp = p2 + (size_t)(2*n+1)*HW;
    const float den1 = 1.f + tt * (fabsf(g1x) + fabsf(g1y));
    p1xp[idx] = (p1xp[idx] + tt*g1x) / den1;
    p1yp[idx] = (p1yp[idx] + tt*g1y) / den1;
    const float den2 = 1.f + tt * (fabsf(g2x) + fabsf(g2y));
    p2xp[idx] = (p2xp[idx] + tt*g2x) / den2;
    p2yp[idx] = (p2yp[idx] + tt*g2y) / den2;
}

extern "C" void kernel_launch(void* const* d_in, const int* in_sizes, int n_in,
                              void* d_out, int out_size, void* d_ws, size_t ws_size,
                              hipStream_t stream) {
    const float* x     = (const float*)d_in[0];
    const float* lam   = (const float*)d_in[1];
    const float* tau   = (const float*)d_in[2];
    const float* theta = (const float*)d_in[3];
    const float* wxv   = (const float*)d_in[4];
    const float* wyv   = (const float*)d_in[5];
    float* u = (float*)d_out;

    const size_t halo_floats = (size_t)(NUM_ITER-1) * NBLK * HPLANES * W;
    const size_t need = halo_floats * sizeof(float)
                      + (size_t)(NUM_ITER-1) * 3 * NBLK * sizeof(int);

    if (ws_size >= need) {
        float* halo = (float*)d_ws;
        int* flags = (int*)((char*)d_ws + halo_floats * sizeof(float));
        void* args[] = { (void*)&x, (void*)&lam, (void*)&tau, (void*)&theta,
                         (void*)&wxv, (void*)&wyv, (void*)&u, (void*)&halo, (void*)&flags };
        hipLaunchCooperativeKernel((void*)tvl1_opp_kernel, dim3(NBLK), dim3(NTHREADS),
                                   args, 0, stream);
    } else {
        float* ws = (float*)d_ws;
        const dim3 grid(NB * H);
        const dim3 block(W);
        precompute_kernel<<<grid, block, 0, stream>>>(x, u, ws);
        for (int it = 0; it < NUM_ITER; ++it) {
            u_kernel<<<grid, block, 0, stream>>>(ws, u, lam, theta, wxv, wyv);
            p_kernel<<<grid, block, 0, stream>>>(u, ws, tau, theta);
        }
    }
}